// Round 9
// baseline (135.637 us; speedup 1.0000x reference)
//
#include <hip/hip_runtime.h>
#include <hip/hip_fp16.h>

#define JN 17

typedef __fp16 h2v __attribute__((ext_vector_type(2)));
typedef _Float16 f16x8 __attribute__((ext_vector_type(8)));
typedef float f32x4 __attribute__((ext_vector_type(4)));

__device__ __forceinline__ float lrelu(float x){ return fmaxf(x, 0.01f*x); }
__device__ __forceinline__ unsigned h2u(h2v h){ unsigned u; __builtin_memcpy(&u, &h, 4); return u; }
__device__ __forceinline__ h2v u2h(unsigned u){ h2v h; __builtin_memcpy(&h, &u, 4); return h; }
__device__ __forceinline__ unsigned pkrtz(float a, float b){ return h2u(__builtin_amdgcn_cvt_pkrtz(a,b)); }
__device__ __forceinline__ float fdot2(unsigned a, unsigned b, float c){
    return __builtin_amdgcn_fdot2(u2h(a), u2h(b), c, false);
}
__device__ __forceinline__ unsigned pkfma(unsigned a, unsigned b, unsigned c){
    h2v r = u2h(a)*u2h(b) + u2h(c);
    return h2u(r);
}
__device__ __forceinline__ f16x8 u4h8(uint4 u){ union{uint4 u; f16x8 h;} c; c.u=u; return c.h; }

// ws header layout (u32 units), first 65536 bytes
#define OFF_PP    0        // 544 f32 : bud + positions @ Wud[32:64]
#define OFF_BQS   544      // 32 f32  : bq * isq
#define OFF_FQ    576      // 512     : Wq*isq B-fragments (2 tiles x 64 lanes x 4 dw)
#define OFF_WD1I  1088     // 512     : Wd1 pairs, rows (p, p+16) [interleaved]
#define OFF_WD2   1600     // 512     : Wd2 pairs, rows (2p, 2p+1)
#define OFF_FUD   2112     // 512     : Wud[0:32] B-fragments
#define OFF_FK    2624     // 512
#define OFF_FV    3136     // 512
#define OFF_TUP   3648     // 544     : Wup rows 32,33 pairs, [j][t][c]
#define OFF_FUP   4192     // 8704    : Wup[0:32] B-fragments per j
#define HDR_BYTES 65536

// ---------------- prep ------------------------------------------------------
__global__ __launch_bounds__(256,1)
void prep_kernel(const void* __restrict__ mraw, const float* __restrict__ pos,
                 const float* __restrict__ Wup,
                 const float* __restrict__ Wud, const float* __restrict__ bud,
                 const float* __restrict__ Wq,  const float* __restrict__ bq,
                 const float* __restrict__ Wk,  const float* __restrict__ Wv,
                 const float* __restrict__ Wd1, const float* __restrict__ Wd2,
                 unsigned* __restrict__ ws32, unsigned* __restrict__ bmask, int B)
{
    int g = blockIdx.x*256 + threadIdx.x;
    const float isq = 0.17677669529663687f;

    // mask mode detection (encodings mutually exclusive given 9-of-17 True)
    const unsigned* mw = (const unsigned*)mraw;
    bool f3f=false, nz=false;
    #pragma unroll
    for (int i=0;i<17;i++){
        unsigned w = mw[i];
        if ((w>>24) == 0x3Fu) f3f = true;
        if (w & 0xFFFFFF00u)  nz  = true;
    }
    int mode = f3f ? 2 : (nz ? 1 : 0);
    if (g < B){
        unsigned bm = 0; size_t base = (size_t)g*JN;
        if (mode == 0){
            const int* mi = (const int*)mraw;
            #pragma unroll
            for (int j=0;j<JN;j++) if (mi[base+j] != 0) bm |= (1u<<j);
        } else if (mode == 1){
            const unsigned char* mb = (const unsigned char*)mraw;
            #pragma unroll
            for (int j=0;j<JN;j++) if (mb[base+j] != 0) bm |= (1u<<j);
        } else {
            const float* mf = (const float*)mraw;
            #pragma unroll
            for (int j=0;j<JN;j++) if (mf[base+j] != 0.f) bm |= (1u<<j);
        }
        bmask[g] = bm;
    }
    if (g < 544){
        int j = g >> 5, h = g & 31;
        float acc = bud[h];
        #pragma unroll
        for (int c=0;c<32;c++) acc = fmaf(pos[j*32+c], Wud[(32+c)*32 + h], acc);
        ((float*)ws32)[OFF_PP + g] = acc;
        int t = (g >> 4) & 1, c = g & 15;
        int col = j*32 + t*16 + c;
        ws32[OFF_TUP + g] = pkrtz(Wup[32*544 + col], Wup[33*544 + col]);
    }
    if (g < 32) ((float*)ws32)[OFF_BQS + g] = bq[g]*isq;
    if (g < 512){
        // B-fragment tables: col = lane&15 (+16*t), k = (lane>>4)*8 + 2*i2 (+1)
        int t = g >> 8, rmn = g & 255, lane = rmn >> 2, i2 = rmn & 3;
        int k0 = (lane>>4)*8 + 2*i2, c = (lane&15) + 16*t;
        ws32[OFF_FUD + g] = pkrtz(Wud[k0*32 + c],     Wud[(k0+1)*32 + c]);
        ws32[OFF_FK  + g] = pkrtz(Wk [k0*32 + c],     Wk [(k0+1)*32 + c]);
        ws32[OFF_FV  + g] = pkrtz(Wv [k0*32 + c],     Wv [(k0+1)*32 + c]);
        ws32[OFF_FQ  + g] = pkrtz(Wq [k0*32 + c]*isq, Wq [(k0+1)*32 + c]*isq);
        // pass2 GEMV tables
        int p = g >> 5, h = g & 31;
        ws32[OFF_WD1I + g] = pkrtz(Wd1[p*32+h],     Wd1[(p+16)*32+h]);
        ws32[OFF_WD2  + g] = pkrtz(Wd2[(2*p)*32+h], Wd2[(2*p+1)*32+h]);
    }
    if (g < 8704){
        int j = g >> 9, r = g & 511, t = r >> 8, rr = r & 255, lane = rr >> 2, i2 = rr & 3;
        int k0 = (lane>>4)*8 + 2*i2;
        int col = j*32 + (lane&15) + 16*t;
        ws32[OFF_FUP + g] = pkrtz(Wup[k0*544 + col], Wup[(k0+1)*544 + col]);
    }
}

// ---------------- fused kernel: 16 samples / block (4 waves) -----------------
// Phase1: MFMA up->uu->k/v/q per j (j split across waves), results to LDS.
// Phase2: 128 lanes = (sample, query); attention + head from LDS.
__global__ __launch_bounds__(256,2)
void fused_kernel(const float* __restrict__ x, const unsigned* __restrict__ bmask,
                  const unsigned* __restrict__ ws32,
                  const float* __restrict__ bup, const float* __restrict__ bk,
                  const float* __restrict__ bv,  const float* __restrict__ bd1,
                  const float* __restrict__ bd2, const float* __restrict__ Ws,
                  const float* __restrict__ bs,  float* __restrict__ out, int B)
{
    __shared__ unsigned ksl[16*17*16];   // k rows, dword = pair (h, h+16), rot-swizzled
    __shared__ unsigned vsl[16*17*16];
    __shared__ unsigned qsl[16*8*16];    // q rows (scaled), occluded-rank indexed
    __shared__ unsigned usl[16*8*16];    // residual up rows
    __shared__ float    als[4][544];     // per-wave repack tile (16 x 34)

    const int tid = threadIdx.x;
    const int wid = tid >> 6, wl = tid & 63;
    const int sb  = blockIdx.x * 16;
    const int srow = wl & 15, g4 = wl >> 4;
    const int smax = B - 1;

    // ---------------- phase 1 ----------------
    {
        f16x8 ax;
        {
            int sA = sb + srow; if (sA > smax) sA = smax;
            const float* xr = x + (size_t)sA*34 + g4*8;
            float2 a0 = *(const float2*)(xr);
            float2 a1 = *(const float2*)(xr+2);
            float2 a2 = *(const float2*)(xr+4);
            float2 a3 = *(const float2*)(xr+6);
            uint4 u; u.x=pkrtz(a0.x,a0.y); u.y=pkrtz(a1.x,a1.y);
            u.z=pkrtz(a2.x,a2.y); u.w=pkrtz(a3.x,a3.y);
            ax = u4h8(u);
        }
        const uint4* wsu4 = (const uint4*)ws32;
        f16x8 fud0 = u4h8(wsu4[OFF_FUD/4 + wl]);
        f16x8 fud1 = u4h8(wsu4[OFF_FUD/4 + 64 + wl]);
        f16x8 fk0  = u4h8(wsu4[OFF_FK/4  + wl]);
        f16x8 fk1  = u4h8(wsu4[OFF_FK/4  + 64 + wl]);
        f16x8 fv0  = u4h8(wsu4[OFF_FV/4  + wl]);
        f16x8 fv1  = u4h8(wsu4[OFF_FV/4  + 64 + wl]);
        f16x8 fq0  = u4h8(wsu4[OFF_FQ/4  + wl]);
        f16x8 fq1  = u4h8(wsu4[OFF_FQ/4  + 64 + wl]);

        const float* ppf = (const float*)ws32;
        float bkv0 = bk[srow],  bkv1 = bk[16+srow];
        float bvv0 = bv[srow],  bvv1 = bv[16+srow];
        float bqv0 = ppf[OFF_BQS + srow], bqv1 = ppf[OFF_BQS + 16 + srow];

        unsigned bmr[4]; unsigned xtp[4];
        #pragma unroll
        for (int reg=0; reg<4; reg++){
            int sr = sb + g4*4 + reg; if (sr > smax) sr = smax;
            bmr[reg] = bmask[sr];
            float2 t = *(const float2*)(x + (size_t)sr*34 + 32);
            xtp[reg] = pkrtz(t.x, t.y);
        }

        // j coverage: wave w -> {w, w+4, w+8, w+12}; wave 3 additionally j=16
        int njl = (wid == 3) ? 5 : 4;
        for (int jj = 0; jj < njl; jj++){
            int j = (jj < 4) ? (wid + jj*4) : 16;
            f16x8 fup0 = u4h8(wsu4[OFF_FUP/4 + j*128 + wl]);
            f16x8 fup1 = u4h8(wsu4[OFF_FUP/4 + j*128 + 64 + wl]);
            unsigned tup0 = ws32[OFF_TUP + j*32 + srow];
            unsigned tup1 = ws32[OFF_TUP + j*32 + 16 + srow];
            float bupv0 = bup[j*32 + srow], bupv1 = bup[j*32 + 16 + srow];
            float ppv0  = ppf[OFF_PP + j*32 + srow], ppv1 = ppf[OFF_PP + j*32 + 16 + srow];

            // up = leaky(x @ Wup_j + b)
            f32x4 up0 = {bupv0,bupv0,bupv0,bupv0};
            f32x4 up1 = {bupv1,bupv1,bupv1,bupv1};
            up0 = __builtin_amdgcn_mfma_f32_16x16x32_f16(ax, fup0, up0, 0,0,0);
            up1 = __builtin_amdgcn_mfma_f32_16x16x32_f16(ax, fup1, up1, 0,0,0);
            #pragma unroll
            for (int reg=0; reg<4; reg++){
                up0[reg] = lrelu(fdot2(xtp[reg], tup0, up0[reg]));
                up1[reg] = lrelu(fdot2(xtp[reg], tup1, up1[reg]));
            }
            // residual rows for occluded joints
            #pragma unroll
            for (int reg=0; reg<4; reg++){
                int r = g4*4 + reg;
                unsigned bm = bmr[reg];
                if (!((bm>>j)&1u)){
                    int rk = __popc((~bm) & ((1u<<j)-1u));
                    int rot = (rk + r + (r>>2)) & 3;
                    usl[(r*8 + rk)*16 + ((srow + 4*rot)&15)] = pkrtz(up0[reg], up1[reg]);
                }
            }
            // repack up (C-layout) -> A-frag via per-wave LDS tile
            #pragma unroll
            for (int reg=0; reg<4; reg++){
                int r = g4*4 + reg;
                als[wid][r*34 + srow]      = up0[reg];
                als[wid][r*34 + 16 + srow] = up1[reg];
            }
            asm volatile("s_waitcnt lgkmcnt(0)" ::: "memory");
            __builtin_amdgcn_sched_barrier(0);
            f16x8 aup;
            {
                const float* rp = &als[wid][srow*34 + g4*8];
                float2 a0=*(const float2*)(rp),   a1=*(const float2*)(rp+2);
                float2 a2=*(const float2*)(rp+4), a3=*(const float2*)(rp+6);
                uint4 u; u.x=pkrtz(a0.x,a0.y); u.y=pkrtz(a1.x,a1.y);
                u.z=pkrtz(a2.x,a2.y); u.w=pkrtz(a3.x,a3.y);
                aup = u4h8(u);
            }
            asm volatile("s_waitcnt lgkmcnt(0)" ::: "memory");
            __builtin_amdgcn_sched_barrier(0);

            // uu = leaky(pp_j + up @ Wud0)
            f32x4 uu0 = {ppv0,ppv0,ppv0,ppv0};
            f32x4 uu1 = {ppv1,ppv1,ppv1,ppv1};
            uu0 = __builtin_amdgcn_mfma_f32_16x16x32_f16(aup, fud0, uu0, 0,0,0);
            uu1 = __builtin_amdgcn_mfma_f32_16x16x32_f16(aup, fud1, uu1, 0,0,0);
            #pragma unroll
            for (int reg=0; reg<4; reg++){ uu0[reg]=lrelu(uu0[reg]); uu1[reg]=lrelu(uu1[reg]); }

            #pragma unroll
            for (int reg=0; reg<4; reg++){
                int r = g4*4 + reg;
                als[wid][r*34 + srow]      = uu0[reg];
                als[wid][r*34 + 16 + srow] = uu1[reg];
            }
            asm volatile("s_waitcnt lgkmcnt(0)" ::: "memory");
            __builtin_amdgcn_sched_barrier(0);
            f16x8 auu;
            {
                const float* rp = &als[wid][srow*34 + g4*8];
                float2 a0=*(const float2*)(rp),   a1=*(const float2*)(rp+2);
                float2 a2=*(const float2*)(rp+4), a3=*(const float2*)(rp+6);
                uint4 u; u.x=pkrtz(a0.x,a0.y); u.y=pkrtz(a1.x,a1.y);
                u.z=pkrtz(a2.x,a2.y); u.w=pkrtz(a3.x,a3.y);
                auu = u4h8(u);
            }
            asm volatile("s_waitcnt lgkmcnt(0)" ::: "memory");
            __builtin_amdgcn_sched_barrier(0);

            // k, v, q
            f32x4 kk0 = {bkv0,bkv0,bkv0,bkv0}, kk1 = {bkv1,bkv1,bkv1,bkv1};
            f32x4 vv0 = {bvv0,bvv0,bvv0,bvv0}, vv1 = {bvv1,bvv1,bvv1,bvv1};
            f32x4 qq0 = {bqv0,bqv0,bqv0,bqv0}, qq1 = {bqv1,bqv1,bqv1,bqv1};
            kk0 = __builtin_amdgcn_mfma_f32_16x16x32_f16(auu, fk0, kk0, 0,0,0);
            kk1 = __builtin_amdgcn_mfma_f32_16x16x32_f16(auu, fk1, kk1, 0,0,0);
            vv0 = __builtin_amdgcn_mfma_f32_16x16x32_f16(auu, fv0, vv0, 0,0,0);
            vv1 = __builtin_amdgcn_mfma_f32_16x16x32_f16(auu, fv1, vv1, 0,0,0);
            qq0 = __builtin_amdgcn_mfma_f32_16x16x32_f16(auu, fq0, qq0, 0,0,0);
            qq1 = __builtin_amdgcn_mfma_f32_16x16x32_f16(auu, fq1, qq1, 0,0,0);

            #pragma unroll
            for (int reg=0; reg<4; reg++){
                int r = g4*4 + reg;
                int rot = (j + r + (r>>2)) & 3;
                int dp = (srow + 4*rot) & 15;
                ksl[(r*17 + j)*16 + dp] = pkrtz(kk0[reg], kk1[reg]);
                vsl[(r*17 + j)*16 + dp] = pkrtz(vv0[reg], vv1[reg]);
                unsigned bm = bmr[reg];
                if (!((bm>>j)&1u)){
                    int rk = __popc((~bm) & ((1u<<j)-1u));
                    int rotq = (rk + r + (r>>2)) & 3;
                    qsl[(r*8 + rk)*16 + ((srow + 4*rotq)&15)] = pkrtz(qq0[reg], qq1[reg]);
                }
            }
        }
    }
    __syncthreads();
    if (tid >= 128) return;

    // ---------------- phase 2 ----------------
    const int s = tid >> 3, q = tid & 7;
    if (sb + s >= B) return;

    // q row (already scaled)
    unsigned qw[16];
    {
        int rot = (q + s + (s>>2)) & 3;
        const unsigned* base = qsl + (s*8 + q)*16;
        #pragma unroll
        for (int a=0;a<4;a++){
            uint4 t = *(const uint4*)(base + ((a + rot)&3)*4);
            qw[4*a]=t.x; qw[4*a+1]=t.y; qw[4*a+2]=t.z; qw[4*a+3]=t.w;
        }
    }
    // scores
    float sc[JN];
    #pragma unroll
    for (int kj=0; kj<JN; kj++){
        unsigned kw[16];
        int rot = (kj + s + (s>>2)) & 3;
        const unsigned* base = ksl + (s*17 + kj)*16;
        #pragma unroll
        for (int a=0;a<4;a++){
            uint4 t = *(const uint4*)(base + ((a + rot)&3)*4);
            kw[4*a]=t.x; kw[4*a+1]=t.y; kw[4*a+2]=t.z; kw[4*a+3]=t.w;
        }
        float s0=0.f,s1=0.f,s2=0.f,s3=0.f;
        #pragma unroll
        for (int p=0;p<16;p+=4){
            s0 = fdot2(qw[p],   kw[p],   s0);
            s1 = fdot2(qw[p+1], kw[p+1], s1);
            s2 = fdot2(qw[p+2], kw[p+2], s2);
            s3 = fdot2(qw[p+3], kw[p+3], s3);
        }
        sc[kj] = (s0+s1)+(s2+s3);
    }
    float m = sc[0];
    #pragma unroll
    for (int kj=1;kj<JN;kj++) m = fmaxf(m, sc[kj]);
    float e[JN]; float sum = 0.f;
    #pragma unroll
    for (int kj=0;kj<JN;kj++){ e[kj] = __expf(sc[kj]-m); sum += e[kj]; }
    float ri = 1.0f/sum;

    // o = att @ v  (f16 pair accumulate, pair = (h, h+16))
    unsigned o[16];
    #pragma unroll
    for (int p=0;p<16;p++) o[p] = 0u;
    #pragma unroll
    for (int kj=0;kj<JN;kj++){
        float w = e[kj]*ri;
        unsigned w2 = pkrtz(w, w);
        unsigned vw[16];
        int rot = (kj + s + (s>>2)) & 3;
        const unsigned* base = vsl + (s*17 + kj)*16;
        #pragma unroll
        for (int a=0;a<4;a++){
            uint4 t = *(const uint4*)(base + ((a + rot)&3)*4);
            vw[4*a]=t.x; vw[4*a+1]=t.y; vw[4*a+2]=t.z; vw[4*a+3]=t.w;
        }
        #pragma unroll
        for (int p=0;p<16;p++) o[p] = pkfma(w2, vw[p], o[p]);
    }

    // d1 = leaky(o @ Wd1 + bd1)
    const unsigned* wd1I = ws32 + OFF_WD1I;
    const unsigned* wd2  = ws32 + OFF_WD2;
    float t[32];
    #pragma unroll
    for (int h=0;h<32;h++) t[h] = bd1[h];
    #pragma unroll
    for (int p=0;p<16;p++){
        unsigned a = o[p];
        #pragma unroll
        for (int h=0;h<32;h++) t[h] = fdot2(a, wd1I[p*32+h], t[h]);
    }
    unsigned tp[16];
    #pragma unroll
    for (int p=0;p<16;p++) tp[p] = pkrtz(lrelu(t[2*p]), lrelu(t[2*p+1]));

    // d2 + residual
    float z[32];
    {
        int rot = (q + s + (s>>2)) & 3;
        const unsigned* base = usl + (s*8 + q)*16;
        #pragma unroll
        for (int a=0;a<4;a++){
            uint4 tt = *(const uint4*)(base + ((a + rot)&3)*4);
            unsigned pw[4] = {tt.x, tt.y, tt.z, tt.w};
            #pragma unroll
            for (int i=0;i<4;i++){
                int p = 4*a + i;
                h2v r = u2h(pw[i]);
                z[p]    = bd2[p]    + (float)r.x;
                z[p+16] = bd2[p+16] + (float)r.y;
            }
        }
    }
    #pragma unroll
    for (int p=0;p<16;p++){
        unsigned a = tp[p];
        #pragma unroll
        for (int h=0;h<32;h++) z[h] = fdot2(a, wd2[p*32+h], z[h]);
    }

    // sigmoid(z @ Ws + bs)
    float y0=0.f, y1=0.f;
    #pragma unroll
    for (int h=0;h<32;h+=2){ y0 = fmaf(z[h], Ws[h], y0); y1 = fmaf(z[h+1], Ws[h+1], y1); }
    float y = y0 + y1 + bs[0];
    out[((size_t)(sb + s))*8 + q] = 1.0f/(1.0f + __expf(-y));
}

extern "C" void kernel_launch(void* const* d_in, const int* in_sizes, int n_in,
                              void* d_out, int out_size, void* d_ws, size_t ws_size,
                              hipStream_t stream) {
    (void)n_in; (void)out_size; (void)ws_size;
    const float* x   = (const float*)d_in[0];
    const void*  m   = d_in[1];
    const float* pos = (const float*)d_in[2];
    const float* Wup = (const float*)d_in[3];  const float* bup = (const float*)d_in[4];
    const float* Wud = (const float*)d_in[5];  const float* bud = (const float*)d_in[6];
    const float* Wq  = (const float*)d_in[7];  const float* bq  = (const float*)d_in[8];
    const float* Wk  = (const float*)d_in[9];  const float* bk  = (const float*)d_in[10];
    const float* Wv  = (const float*)d_in[11]; const float* bv  = (const float*)d_in[12];
    const float* Wd1 = (const float*)d_in[13]; const float* bd1 = (const float*)d_in[14];
    const float* Wd2 = (const float*)d_in[15]; const float* bd2 = (const float*)d_in[16];
    const float* Ws  = (const float*)d_in[17]; const float* bs  = (const float*)d_in[18];
    float* out = (float*)d_out;
    int B = in_sizes[0] / (JN*2);

    unsigned char* wsb = (unsigned char*)d_ws;
    unsigned* ws32  = (unsigned*)wsb;                 // 64 KB table header
    unsigned* bmask = (unsigned*)(wsb + HDR_BYTES);   // B u32

    prep_kernel<<<(B+255)/256, 256, 0, stream>>>(m, pos, Wup, Wud, bud, Wq, bq,
                                                 Wk, Wv, Wd1, Wd2, ws32, bmask, B);
    fused_kernel<<<(B+15)/16, 256, 0, stream>>>(x, bmask, ws32, bup, bk, bv,
                                                bd1, bd2, Ws, bs, out, B);
}

// Round 10
// 99.668 us; speedup vs baseline: 1.3609x; 1.3609x over previous
//
#include <hip/hip_runtime.h>
#include <hip/hip_fp16.h>

#define JN 17

typedef __fp16 h2v __attribute__((ext_vector_type(2)));
typedef _Float16 f16x8 __attribute__((ext_vector_type(8)));
typedef float f32x4 __attribute__((ext_vector_type(4)));

__device__ __forceinline__ float lrelu(float x){ return fmaxf(x, 0.01f*x); }
__device__ __forceinline__ unsigned h2u(h2v h){ unsigned u; __builtin_memcpy(&u, &h, 4); return u; }
__device__ __forceinline__ h2v u2h(unsigned u){ h2v h; __builtin_memcpy(&h, &u, 4); return h; }
__device__ __forceinline__ unsigned pkrtz(float a, float b){ return h2u(__builtin_amdgcn_cvt_pkrtz(a,b)); }
__device__ __forceinline__ float fdot2(unsigned a, unsigned b, float c){
    return __builtin_amdgcn_fdot2(u2h(a), u2h(b), c, false);
}
__device__ __forceinline__ unsigned pkfma(unsigned a, unsigned b, unsigned c){
    h2v r = u2h(a)*u2h(b) + u2h(c);
    return h2u(r);
}
__device__ __forceinline__ f16x8 u4h8(uint4 u){ union{uint4 u; f16x8 h;} c; c.u=u; return c.h; }
__device__ __forceinline__ f32x4 mk4(float4 v){ f32x4 r; r[0]=v.x; r[1]=v.y; r[2]=v.z; r[3]=v.w; return r; }

// C(t0,t1) -> B-frag of next MFMA via cross-lane permute (values post-activation).
// c0 = tile0 rows (h=4*g4+reg), c1 = tile1 (h+16). Target needs k=8*g4..+7 pairs.
__device__ __forceinline__ f16x8 repack(f32x4 c0, f32x4 c1, int srcA, int srcB, bool selLo){
    unsigned pkA = pkrtz(c0[0], c0[1]);
    unsigned pkB = pkrtz(c0[2], c0[3]);
    unsigned pkC = pkrtz(c1[0], c1[1]);
    unsigned pkD = pkrtz(c1[2], c1[3]);
    unsigned rA0 = (unsigned)__shfl((int)pkA, srcA, 64);
    unsigned rB0 = (unsigned)__shfl((int)pkB, srcA, 64);
    unsigned rC0 = (unsigned)__shfl((int)pkC, srcA, 64);
    unsigned rD0 = (unsigned)__shfl((int)pkD, srcA, 64);
    unsigned rA1 = (unsigned)__shfl((int)pkA, srcB, 64);
    unsigned rB1 = (unsigned)__shfl((int)pkB, srcB, 64);
    unsigned rC1 = (unsigned)__shfl((int)pkC, srcB, 64);
    unsigned rD1 = (unsigned)__shfl((int)pkD, srcB, 64);
    uint4 u;
    u.x = selLo ? rA0 : rC0;
    u.y = selLo ? rB0 : rD0;
    u.z = selLo ? rA1 : rC1;
    u.w = selLo ? rB1 : rD1;
    return u4h8(u);
}

// ws header layout (u32 units), first 65536 bytes
#define OFF_PP    0        // 544 f32 : bud + positions @ Wud[32:64]
#define OFF_BQS   544      // 32 f32  : bq * isq
#define OFF_FQ    576      // 512     : Wq*isq fragments
#define OFF_WD1I  1088     // 512     : Wd1 pairs, rows (p, p+16) [interleaved]
#define OFF_WD2   1600     // 512     : Wd2 pairs, rows (2p, 2p+1)
#define OFF_FUD   2112     // 512
#define OFF_FK    2624     // 512
#define OFF_FV    3136     // 512
#define OFF_TUP   3648     // 544     : Wup rows 32,33 pairs, [j][t][c]
#define OFF_FUP   4192     // 8704    : Wup[0:32] fragments per j
#define HDR_BYTES 65536

#define KSTRIDE 276        // dwords per sample slab of ksl/vsl (17*16 + 4 pad)
#define QSTRIDE 132        // dwords per sample slab of qsl/usl (8*16 + 4 pad)

// ---------------- prep ------------------------------------------------------
__global__ __launch_bounds__(256,1)
void prep_kernel(const void* __restrict__ mraw, const float* __restrict__ pos,
                 const float* __restrict__ Wup,
                 const float* __restrict__ Wud, const float* __restrict__ bud,
                 const float* __restrict__ Wq,  const float* __restrict__ bq,
                 const float* __restrict__ Wk,  const float* __restrict__ Wv,
                 const float* __restrict__ Wd1, const float* __restrict__ Wd2,
                 unsigned* __restrict__ ws32, unsigned* __restrict__ bmask, int B)
{
    int g = blockIdx.x*256 + threadIdx.x;
    const float isq = 0.17677669529663687f;

    // mask mode detection (encodings mutually exclusive given 9-of-17 True)
    const unsigned* mw = (const unsigned*)mraw;
    bool f3f=false, nz=false;
    #pragma unroll
    for (int i=0;i<17;i++){
        unsigned w = mw[i];
        if ((w>>24) == 0x3Fu) f3f = true;
        if (w & 0xFFFFFF00u)  nz  = true;
    }
    int mode = f3f ? 2 : (nz ? 1 : 0);
    if (g < B){
        unsigned bm = 0; size_t base = (size_t)g*JN;
        if (mode == 0){
            const int* mi = (const int*)mraw;
            #pragma unroll
            for (int j=0;j<JN;j++) if (mi[base+j] != 0) bm |= (1u<<j);
        } else if (mode == 1){
            const unsigned char* mb = (const unsigned char*)mraw;
            #pragma unroll
            for (int j=0;j<JN;j++) if (mb[base+j] != 0) bm |= (1u<<j);
        } else {
            const float* mf = (const float*)mraw;
            #pragma unroll
            for (int j=0;j<JN;j++) if (mf[base+j] != 0.f) bm |= (1u<<j);
        }
        bmask[g] = bm;
    }
    if (g < 544){
        int j = g >> 5, h = g & 31;
        float acc = bud[h];
        #pragma unroll
        for (int c=0;c<32;c++) acc = fmaf(pos[j*32+c], Wud[(32+c)*32 + h], acc);
        ((float*)ws32)[OFF_PP + g] = acc;
        int t = (g >> 4) & 1, c = g & 15;
        int col = j*32 + t*16 + c;
        ws32[OFF_TUP + g] = pkrtz(Wup[32*544 + col], Wup[33*544 + col]);
    }
    if (g < 32) ((float*)ws32)[OFF_BQS + g] = bq[g]*isq;
    if (g < 512){
        // fragment tables: h = (lane&15)+16t, k = (lane>>4)*8 + 2*i2 (+1)
        int t = g >> 8, rmn = g & 255, lane = rmn >> 2, i2 = rmn & 3;
        int k0 = (lane>>4)*8 + 2*i2, c = (lane&15) + 16*t;
        ws32[OFF_FUD + g] = pkrtz(Wud[k0*32 + c],     Wud[(k0+1)*32 + c]);
        ws32[OFF_FK  + g] = pkrtz(Wk [k0*32 + c],     Wk [(k0+1)*32 + c]);
        ws32[OFF_FV  + g] = pkrtz(Wv [k0*32 + c],     Wv [(k0+1)*32 + c]);
        ws32[OFF_FQ  + g] = pkrtz(Wq [k0*32 + c]*isq, Wq [(k0+1)*32 + c]*isq);
        int p = g >> 5, h = g & 31;
        ws32[OFF_WD1I + g] = pkrtz(Wd1[p*32+h],     Wd1[(p+16)*32+h]);
        ws32[OFF_WD2  + g] = pkrtz(Wd2[(2*p)*32+h], Wd2[(2*p+1)*32+h]);
    }
    if (g < 8704){
        int j = g >> 9, r = g & 511, t = r >> 8, rr = r & 255, lane = rr >> 2, i2 = rr & 3;
        int k0 = (lane>>4)*8 + 2*i2;
        int col = j*32 + (lane&15) + 16*t;
        ws32[OFF_FUP + g] = pkrtz(Wup[k0*544 + col], Wup[(k0+1)*544 + col]);
    }
}

// ---------------- fused kernel: 16 samples / block (4 waves) -----------------
// Phase1 (transposed MFMA): D^T = W^T * act^T; sample stays in lane&15; repack
// between chained GEMMs is 8 shfl + 4 selects (no LDS tile, no waits).
// Phase2: 128 lanes = (sample, query); attention + head from LDS.
__global__ __launch_bounds__(256,3)
void fused_kernel(const float* __restrict__ x, const unsigned* __restrict__ bmask,
                  const unsigned* __restrict__ ws32,
                  const float* __restrict__ bup, const float* __restrict__ bk,
                  const float* __restrict__ bv,  const float* __restrict__ bd1,
                  const float* __restrict__ bd2, const float* __restrict__ Ws,
                  const float* __restrict__ bs,  float* __restrict__ out, int B)
{
    __shared__ unsigned ksl[16*KSTRIDE];   // k rows, dword = pair (h, h+16), group-rot
    __shared__ unsigned vsl[16*KSTRIDE];
    __shared__ unsigned qsl[16*QSTRIDE];   // q rows (scaled), occluded-rank indexed
    __shared__ unsigned usl[16*QSTRIDE];   // residual up rows

    const int tid = threadIdx.x;
    const int wid = tid >> 6, wl = tid & 63;
    const int sb  = blockIdx.x * 16;
    const int s   = wl & 15, g4 = wl >> 4;
    const int smax = B - 1;

    // ---------------- phase 1 ----------------
    {
        int sA = sb + s; if (sA > smax) sA = smax;
        f16x8 ax;
        {
            const float* xr = x + (size_t)sA*34 + g4*8;
            float2 a0 = *(const float2*)(xr);
            float2 a1 = *(const float2*)(xr+2);
            float2 a2 = *(const float2*)(xr+4);
            float2 a3 = *(const float2*)(xr+6);
            uint4 u; u.x=pkrtz(a0.x,a0.y); u.y=pkrtz(a1.x,a1.y);
            u.z=pkrtz(a2.x,a2.y); u.w=pkrtz(a3.x,a3.y);
            ax = u4h8(u);
        }
        const unsigned bm = bmask[sA];
        float2 xt2 = *(const float2*)(x + (size_t)sA*34 + 32);
        const unsigned xtp = pkrtz(xt2.x, xt2.y);

        const uint4* wsu4 = (const uint4*)ws32;
        f16x8 fud0 = u4h8(wsu4[OFF_FUD/4 + wl]);
        f16x8 fud1 = u4h8(wsu4[OFF_FUD/4 + 64 + wl]);
        f16x8 fk0  = u4h8(wsu4[OFF_FK/4  + wl]);
        f16x8 fk1  = u4h8(wsu4[OFF_FK/4  + 64 + wl]);
        f16x8 fv0  = u4h8(wsu4[OFF_FV/4  + wl]);
        f16x8 fv1  = u4h8(wsu4[OFF_FV/4  + 64 + wl]);
        f16x8 fq0  = u4h8(wsu4[OFF_FQ/4  + wl]);
        f16x8 fq1  = u4h8(wsu4[OFF_FQ/4  + 64 + wl]);

        const float* ppf = (const float*)ws32;
        float4 bk0 = *(const float4*)(bk + g4*4);
        float4 bk1 = *(const float4*)(bk + 16 + g4*4);
        float4 bv0 = *(const float4*)(bv + g4*4);
        float4 bv1 = *(const float4*)(bv + 16 + g4*4);
        float4 bq0 = *(const float4*)(ppf + OFF_BQS + g4*4);
        float4 bq1 = *(const float4*)(ppf + OFF_BQS + 16 + g4*4);

        const int srcA = s + 32*(g4 & 1);
        const int srcB = srcA + 16;
        const bool selLo = (g4 < 2);

        const int njl = (wid == 3) ? 5 : 4;
        for (int jj = 0; jj < njl; jj++){
            const int j = (jj < 4) ? (wid + jj*4) : 16;
            f16x8 fup0 = u4h8(wsu4[OFF_FUP/4 + j*128 + wl]);
            f16x8 fup1 = u4h8(wsu4[OFF_FUP/4 + j*128 + 64 + wl]);
            float4 bu0 = *(const float4*)(bup + j*32 + g4*4);
            float4 bu1 = *(const float4*)(bup + j*32 + 16 + g4*4);
            float4 pp0 = *(const float4*)(ppf + OFF_PP + j*32 + g4*4);
            float4 pp1 = *(const float4*)(ppf + OFF_PP + j*32 + 16 + g4*4);
            uint4 tu0 = *(const uint4*)(ws32 + OFF_TUP + j*32 + g4*4);
            uint4 tu1 = *(const uint4*)(ws32 + OFF_TUP + j*32 + 16 + g4*4);

            // up^T = W_up^T x^T + (bias + x-tail) ; C-init carries bias+tail
            f32x4 up0, up1;
            up0[0] = fdot2(xtp, tu0.x, bu0.x); up0[1] = fdot2(xtp, tu0.y, bu0.y);
            up0[2] = fdot2(xtp, tu0.z, bu0.z); up0[3] = fdot2(xtp, tu0.w, bu0.w);
            up1[0] = fdot2(xtp, tu1.x, bu1.x); up1[1] = fdot2(xtp, tu1.y, bu1.y);
            up1[2] = fdot2(xtp, tu1.z, bu1.z); up1[3] = fdot2(xtp, tu1.w, bu1.w);
            up0 = __builtin_amdgcn_mfma_f32_16x16x32_f16(fup0, ax, up0, 0,0,0);
            up1 = __builtin_amdgcn_mfma_f32_16x16x32_f16(fup1, ax, up1, 0,0,0);
            #pragma unroll
            for (int r=0;r<4;r++){ up0[r] = lrelu(up0[r]); up1[r] = lrelu(up1[r]); }

            const bool occ = !((bm>>j)&1u);
            const int rk = __popc((~bm) & ((1u<<j)-1u));
            if (occ){
                int rotq = (rk + s + (s>>2)) & 3;
                uint4 u;
                u.x = pkrtz(up0[0], up1[0]); u.y = pkrtz(up0[1], up1[1]);
                u.z = pkrtz(up0[2], up1[2]); u.w = pkrtz(up0[3], up1[3]);
                *(uint4*)&usl[s*QSTRIDE + rk*16 + ((g4 + rotq)&3)*4] = u;
            }
            f16x8 aup = repack(up0, up1, srcA, srcB, selLo);

            // uu^T = W_ud^T up^T + pp
            f32x4 uu0 = mk4(pp0), uu1 = mk4(pp1);
            uu0 = __builtin_amdgcn_mfma_f32_16x16x32_f16(fud0, aup, uu0, 0,0,0);
            uu1 = __builtin_amdgcn_mfma_f32_16x16x32_f16(fud1, aup, uu1, 0,0,0);
            #pragma unroll
            for (int r=0;r<4;r++){ uu0[r] = lrelu(uu0[r]); uu1[r] = lrelu(uu1[r]); }
            f16x8 auu = repack(uu0, uu1, srcA, srcB, selLo);

            // k, v, q
            f32x4 kk0 = mk4(bk0), kk1 = mk4(bk1);
            f32x4 vv0 = mk4(bv0), vv1 = mk4(bv1);
            f32x4 qq0 = mk4(bq0), qq1 = mk4(bq1);
            kk0 = __builtin_amdgcn_mfma_f32_16x16x32_f16(fk0, auu, kk0, 0,0,0);
            kk1 = __builtin_amdgcn_mfma_f32_16x16x32_f16(fk1, auu, kk1, 0,0,0);
            vv0 = __builtin_amdgcn_mfma_f32_16x16x32_f16(fv0, auu, vv0, 0,0,0);
            vv1 = __builtin_amdgcn_mfma_f32_16x16x32_f16(fv1, auu, vv1, 0,0,0);
            qq0 = __builtin_amdgcn_mfma_f32_16x16x32_f16(fq0, auu, qq0, 0,0,0);
            qq1 = __builtin_amdgcn_mfma_f32_16x16x32_f16(fq1, auu, qq1, 0,0,0);

            const int rot = (j + s + (s>>2)) & 3;
            const int grp = ((g4 + rot)&3)*4;
            uint4 kp, vp;
            kp.x = pkrtz(kk0[0], kk1[0]); kp.y = pkrtz(kk0[1], kk1[1]);
            kp.z = pkrtz(kk0[2], kk1[2]); kp.w = pkrtz(kk0[3], kk1[3]);
            vp.x = pkrtz(vv0[0], vv1[0]); vp.y = pkrtz(vv0[1], vv1[1]);
            vp.z = pkrtz(vv0[2], vv1[2]); vp.w = pkrtz(vv0[3], vv1[3]);
            *(uint4*)&ksl[s*KSTRIDE + j*16 + grp] = kp;
            *(uint4*)&vsl[s*KSTRIDE + j*16 + grp] = vp;
            if (occ){
                int rotq = (rk + s + (s>>2)) & 3;
                uint4 qp4;
                qp4.x = pkrtz(qq0[0], qq1[0]); qp4.y = pkrtz(qq0[1], qq1[1]);
                qp4.z = pkrtz(qq0[2], qq1[2]); qp4.w = pkrtz(qq0[3], qq1[3]);
                *(uint4*)&qsl[s*QSTRIDE + rk*16 + ((g4 + rotq)&3)*4] = qp4;
            }
        }
    }
    __syncthreads();
    if (tid >= 128) return;

    // ---------------- phase 2 ----------------
    const int s2 = tid >> 3, q = tid & 7;
    if (sb + s2 >= B) return;

    unsigned qw[16];
    {
        int rot = (q + s2 + (s2>>2)) & 3;
        const unsigned* base = qsl + s2*QSTRIDE + q*16;
        #pragma unroll
        for (int a=0;a<4;a++){
            uint4 t = *(const uint4*)(base + ((a + rot)&3)*4);
            qw[4*a]=t.x; qw[4*a+1]=t.y; qw[4*a+2]=t.z; qw[4*a+3]=t.w;
        }
    }
    float sc[JN];
    #pragma unroll
    for (int kj=0; kj<JN; kj++){
        unsigned kw[16];
        int rot = (kj + s2 + (s2>>2)) & 3;
        const unsigned* base = ksl + s2*KSTRIDE + kj*16;
        #pragma unroll
        for (int a=0;a<4;a++){
            uint4 t = *(const uint4*)(base + ((a + rot)&3)*4);
            kw[4*a]=t.x; kw[4*a+1]=t.y; kw[4*a+2]=t.z; kw[4*a+3]=t.w;
        }
        float s0=0.f,s1=0.f,s2a=0.f,s3=0.f;
        #pragma unroll
        for (int p=0;p<16;p+=4){
            s0  = fdot2(qw[p],   kw[p],   s0);
            s1  = fdot2(qw[p+1], kw[p+1], s1);
            s2a = fdot2(qw[p+2], kw[p+2], s2a);
            s3  = fdot2(qw[p+3], kw[p+3], s3);
        }
        sc[kj] = (s0+s1)+(s2a+s3);
    }
    float m = sc[0];
    #pragma unroll
    for (int kj=1;kj<JN;kj++) m = fmaxf(m, sc[kj]);
    float e[JN]; float sum = 0.f;
    #pragma unroll
    for (int kj=0;kj<JN;kj++){ e[kj] = __expf(sc[kj]-m); sum += e[kj]; }
    float ri = 1.0f/sum;

    unsigned o[16];
    #pragma unroll
    for (int p=0;p<16;p++) o[p] = 0u;
    #pragma unroll
    for (int kj=0;kj<JN;kj++){
        float w = e[kj]*ri;
        unsigned w2 = pkrtz(w, w);
        unsigned vw[16];
        int rot = (kj + s2 + (s2>>2)) & 3;
        const unsigned* base = vsl + s2*KSTRIDE + kj*16;
        #pragma unroll
        for (int a=0;a<4;a++){
            uint4 t = *(const uint4*)(base + ((a + rot)&3)*4);
            vw[4*a]=t.x; vw[4*a+1]=t.y; vw[4*a+2]=t.z; vw[4*a+3]=t.w;
        }
        #pragma unroll
        for (int p=0;p<16;p++) o[p] = pkfma(w2, vw[p], o[p]);
    }

    const unsigned* wd1I = ws32 + OFF_WD1I;
    const unsigned* wd2  = ws32 + OFF_WD2;
    float t[32];
    #pragma unroll
    for (int h=0;h<32;h++) t[h] = bd1[h];
    #pragma unroll
    for (int p=0;p<16;p++){
        unsigned a = o[p];
        #pragma unroll
        for (int h=0;h<32;h++) t[h] = fdot2(a, wd1I[p*32+h], t[h]);
    }
    unsigned tp[16];
    #pragma unroll
    for (int p=0;p<16;p++) tp[p] = pkrtz(lrelu(t[2*p]), lrelu(t[2*p+1]));

    float z[32];
    {
        int rot = (q + s2 + (s2>>2)) & 3;
        const unsigned* base = usl + s2*QSTRIDE + q*16;
        #pragma unroll
        for (int a=0;a<4;a++){
            uint4 tt = *(const uint4*)(base + ((a + rot)&3)*4);
            unsigned pw[4] = {tt.x, tt.y, tt.z, tt.w};
            #pragma unroll
            for (int i=0;i<4;i++){
                int p = 4*a + i;
                h2v r = u2h(pw[i]);
                z[p]    = bd2[p]    + (float)r.x;
                z[p+16] = bd2[p+16] + (float)r.y;
            }
        }
    }
    #pragma unroll
    for (int p=0;p<16;p++){
        unsigned a = tp[p];
        #pragma unroll
        for (int h=0;h<32;h++) z[h] = fdot2(a, wd2[p*32+h], z[h]);
    }

    float y0=0.f, y1=0.f;
    #pragma unroll
    for (int h=0;h<32;h+=2){ y0 = fmaf(z[h], Ws[h], y0); y1 = fmaf(z[h+1], Ws[h+1], y1); }
    float y = y0 + y1 + bs[0];
    out[((size_t)(sb + s2))*8 + q] = 1.0f/(1.0f + __expf(-y));
}

extern "C" void kernel_launch(void* const* d_in, const int* in_sizes, int n_in,
                              void* d_out, int out_size, void* d_ws, size_t ws_size,
                              hipStream_t stream) {
    (void)n_in; (void)out_size; (void)ws_size;
    const float* x   = (const float*)d_in[0];
    const void*  m   = d_in[1];
    const float* pos = (const float*)d_in[2];
    const float* Wup = (const float*)d_in[3];  const float* bup = (const float*)d_in[4];
    const float* Wud = (const float*)d_in[5];  const float* bud = (const float*)d_in[6];
    const float* Wq  = (const float*)d_in[7];  const float* bq  = (const float*)d_in[8];
    const float* Wk  = (const float*)d_in[9];  const float* bk  = (const float*)d_in[10];
    const float* Wv  = (const float*)d_in[11]; const float* bv  = (const float*)d_in[12];
    const float* Wd1 = (const float*)d_in[13]; const float* bd1 = (const float*)d_in[14];
    const float* Wd2 = (const float*)d_in[15]; const float* bd2 = (const float*)d_in[16];
    const float* Ws  = (const float*)d_in[17]; const float* bs  = (const float*)d_in[18];
    float* out = (float*)d_out;
    int B = in_sizes[0] / (JN*2);

    unsigned char* wsb = (unsigned char*)d_ws;
    unsigned* ws32  = (unsigned*)wsb;                 // 64 KB table header
    unsigned* bmask = (unsigned*)(wsb + HDR_BYTES);   // B u32

    prep_kernel<<<(B+255)/256, 256, 0, stream>>>(m, pos, Wup, Wud, bud, Wq, bq,
                                                 Wk, Wv, Wd1, Wd2, ws32, bmask, B);
    fused_kernel<<<(B+15)/16, 256, 0, stream>>>(x, bmask, ws32, bup, bk, bv,
                                                bd1, bd2, Ws, bs, out, B);
}